// Round 1
// 732.148 us; speedup vs baseline: 1.6860x; 1.6860x over previous
//
#include <hip/hip_runtime.h>

#define B_   2
#define Q_   1568
#define C_   768
#define C2_  1536
#define H_   12
#define D_   64
#define F_   8
#define S_   196
#define N_   1568
constexpr float SCALE = 0.125f;   // d^-0.5 = 64^-0.5

typedef __bf16 bf16_t;
typedef __bf16 bf16x8 __attribute__((ext_vector_type(8)));
typedef __bf16 bf16x4 __attribute__((ext_vector_type(4)));
typedef float  f32x4  __attribute__((ext_vector_type(4)));

#define AS_G __attribute__((address_space(1)))
#define AS_L __attribute__((address_space(3)))

__device__ inline void load_lds16(const void* g, void* l) {
    __builtin_amdgcn_global_load_lds((const AS_G unsigned int*)g,
                                     (AS_L unsigned int*)l, 16, 0, 0);
}

// ---------------------------------------------------------------------------
// fp32 -> bf16 elementwise convert (n % 4 == 0)
// ---------------------------------------------------------------------------
__global__ __launch_bounds__(256) void cvt_bf16(
    const float* __restrict__ in, bf16_t* __restrict__ out, int n4)
{
    int i = blockIdx.x * 256 + threadIdx.x;
    if (i < n4) {
        float4 v = ((const float4*)in)[i];
        bf16x4 o = { (bf16_t)v.x, (bf16_t)v.y, (bf16_t)v.z, (bf16_t)v.w };
        ((bf16x4*)out)[i] = o;
    }
}

// ---------------------------------------------------------------------------
// W[K,N] fp32 -> Wt[N,K] bf16 (transpose+convert). K,N % 32 == 0.
// ---------------------------------------------------------------------------
__global__ __launch_bounds__(256) void transpose_cvt(
    const float* __restrict__ W, bf16_t* __restrict__ Wt, int K, int N)
{
    __shared__ float tile[32][33];
    const int k0 = blockIdx.y * 32, n0 = blockIdx.x * 32;
    const int t = threadIdx.x;
    const int tx = t & 31, ty = t >> 5;          // ty 0..7
#pragma unroll
    for (int i = 0; i < 4; i++)
        tile[ty + i * 8][tx] = W[(size_t)(k0 + ty + i * 8) * N + n0 + tx];
    __syncthreads();
#pragma unroll
    for (int i = 0; i < 4; i++)
        Wt[(size_t)(n0 + ty + i * 8) * K + k0 + tx] = (bf16_t)tile[tx][ty + i * 8];
}

// ---------------------------------------------------------------------------
// bf16 MFMA GEMM: C[M,N] = A[M,K] @ Bt[N,K]^T (+bias). C fp32 optional,
// Cbf bf16 optional. 128x128 tile, BK=32, 256 threads.
// ---------------------------------------------------------------------------
__global__ __launch_bounds__(256) void gemm_mfma(
    const bf16_t* __restrict__ A, const bf16_t* __restrict__ Bt,
    float* __restrict__ C, bf16_t* __restrict__ Cbf,
    int M, int N, int K, const float* __restrict__ bias)
{
    __shared__ bf16_t As[128 * 32];
    __shared__ bf16_t Bs[128 * 32];
    const int n0 = blockIdx.x * 128;
    const int m0 = blockIdx.y * 128;
    const int t = threadIdx.x;
    const int lane = t & 63;
    const int wv = t >> 6;                 // wave 0..3
    const int wm = wv >> 1, wn = wv & 1;   // 2x2 wave grid, 64x64 each
    const int lane15 = lane & 15, quad = lane >> 4;

    f32x4 acc[4][4];
#pragma unroll
    for (int i = 0; i < 4; i++)
#pragma unroll
        for (int j = 0; j < 4; j++) acc[i][j] = (f32x4){0.f, 0.f, 0.f, 0.f};

    for (int k0 = 0; k0 < K; k0 += 32) {
#pragma unroll
        for (int half = 0; half < 2; half++) {
            int c = half * 256 + t;        // chunk id 0..511
            int row = c >> 2, kc = c & 3;
            int rg = m0 + row; if (rg >= M) rg = M - 1;
            load_lds16(A + (size_t)rg * K + k0 + kc * 8,
                       (char*)As + (half * 256 + wv * 64) * 16);
            load_lds16(Bt + (size_t)(n0 + row) * K + k0 + kc * 8,
                       (char*)Bs + (half * 256 + wv * 64) * 16);
        }
        __syncthreads();

        bf16x8 af[4], bfr[4];
#pragma unroll
        for (int i = 0; i < 4; i++) {
            af[i]  = *(const bf16x8*)(As + (wm * 64 + i * 16 + lane15) * 32 + quad * 8);
            bfr[i] = *(const bf16x8*)(Bs + (wn * 64 + i * 16 + lane15) * 32 + quad * 8);
        }
#pragma unroll
        for (int i = 0; i < 4; i++)
#pragma unroll
            for (int j = 0; j < 4; j++)
                acc[i][j] = __builtin_amdgcn_mfma_f32_16x16x32_bf16(af[i], bfr[j], acc[i][j], 0, 0, 0);
        __syncthreads();
    }

#pragma unroll
    for (int i = 0; i < 4; i++) {
#pragma unroll
        for (int j = 0; j < 4; j++) {
            int col = n0 + wn * 64 + j * 16 + lane15;
            float bb = bias ? bias[col] : 0.f;
#pragma unroll
            for (int r = 0; r < 4; r++) {
                int row = m0 + wm * 64 + i * 16 + quad * 4 + r;
                if (row < M) {
                    float v = acc[i][j][r] + bb;
                    if (C)   C[(size_t)row * N + col] = v;
                    if (Cbf) Cbf[(size_t)row * N + col] = (bf16_t)v;
                }
            }
        }
    }
}

// ---------------------------------------------------------------------------
// Fused stage-1 attention: per (z=b*H+h, q-tile of 112, frame f):
//   S = scale * Q @ K^T  (MFMA, bf16 in / fp32 acc)  -> write out1 (fp32)
//   P = softmax_s(S)     (wave-parallel shfl reduce)
//   x = P @ V            (MFMA, P round-tripped via LDS as bf16, V^T in LDS)
// Grid (F=8, 14, 24), 448 threads (7 waves, one 16-row M-tile each).
// Keys padded 196->208 for QK^T (13 n-tiles), ->224 for PV (7 k-chunks).
// LDS: Vt[64][232] + Ps[7][16][232] = 81,664 B (2 blocks/CU).
// ---------------------------------------------------------------------------
__global__ __launch_bounds__(448, 4) void attn1_fused(
    const bf16_t* __restrict__ qb, const bf16_t* __restrict__ kvb,
    float* __restrict__ out1, bf16_t* __restrict__ x)
{
    __shared__ bf16_t Vt[64 * 232];          // V transposed: [d][s], s padded to 224
    __shared__ bf16_t Ps[7 * 16 * 232];      // per-wave P tile [16 q][s padded]
    const int f = blockIdx.x, qt = blockIdx.y, z = blockIdx.z;
    const int b = z / H_, h = z - b * H_;
    const int t = threadIdx.x;
    const int lane = t & 63, w = t >> 6;     // wave 0..6
    const int lane15 = lane & 15, quad = lane >> 4;

    const size_t kvBase = ((size_t)b * N_ + (size_t)f * S_) * C2_;

    // ---- zero V pad cols s in [196,224) ----
#pragma unroll
    for (int i = 0; i < 4; i++) {
        int e = t + 448 * i;                 // 0..1791 = 64*28
        if (e < 64 * 28) {
            int dd = e / 28;
            int s  = S_ + (e - dd * 28);
            Vt[dd * 232 + s] = (bf16_t)0.f;
        }
    }
    // ---- stage V transposed: Vt[d][s] = V[s][d] ----
    // lanes within a wave take consecutive s (conflict-free ds_writes);
    // element index j stays compile-time (no scratch spill).
#pragma unroll
    for (int i = 0; i < 4; i++) {
        int e = t + 448 * i;                 // 0..1567 = 8*196
        if (e < 8 * S_) {
            int dg = e / S_, s = e - dg * S_;
            bf16x8 v = *(const bf16x8*)(kvb + kvBase + (size_t)s * C2_ + C_ + h * D_ + dg * 8);
#pragma unroll
            for (int j = 0; j < 8; j++)
                Vt[(dg * 8 + j) * 232 + s] = v[j];
        }
    }
    // ---- zero own-wave P pad cols [208,224) ----
    bf16_t* Pw = Ps + w * (16 * 232);
    {
        int prow = lane >> 2, c0 = 208 + (lane & 3) * 4;
        *(bf16x4*)(Pw + prow * 232 + c0) =
            (bf16x4){(bf16_t)0.f, (bf16_t)0.f, (bf16_t)0.f, (bf16_t)0.f};
    }
    __syncthreads();

    // ---- Q A-frags: rows w*16 + lane15, d split in two k-chunks ----
    const int qrow = qt * 112 + w * 16 + lane15;
    const bf16_t* qp = qb + ((size_t)b * Q_ + qrow) * C_ + h * D_ + quad * 8;
    bf16x8 qa0 = *(const bf16x8*)(qp);
    bf16x8 qa1 = *(const bf16x8*)(qp + 32);

    // ---- QK^T: 13 n-tiles of 16 keys, K frags loaded from global ----
    f32x4 acc[13];
#pragma unroll
    for (int n = 0; n < 13; n++) acc[n] = (f32x4){0.f, 0.f, 0.f, 0.f};
#pragma unroll
    for (int n = 0; n < 13; n++) {
        int srow = n * 16 + lane15; if (srow > S_ - 1) srow = S_ - 1;  // clamp pad rows
        const bf16_t* kp = kvb + kvBase + (size_t)srow * C2_ + h * D_ + quad * 8;
        bf16x8 kb0 = *(const bf16x8*)(kp);
        bf16x8 kb1 = *(const bf16x8*)(kp + 32);
        acc[n] = __builtin_amdgcn_mfma_f32_16x16x32_bf16(qa0, kb0, acc[n], 0, 0, 0);
        acc[n] = __builtin_amdgcn_mfma_f32_16x16x32_bf16(qa1, kb1, acc[n], 0, 0, 0);
    }

    // acc[n][r] = S[q = w*16 + quad*4 + r][s = n*16 + lane15]
    // ---- scale, write logits (output 1), mask pad ----
    const size_t o1base = ((size_t)z * Q_ + qt * 112 + w * 16 + quad * 4) * N_ + (size_t)f * S_;
#pragma unroll
    for (int n = 0; n < 13; n++) {
        int s = n * 16 + lane15;
        bool valid = s < S_;
#pragma unroll
        for (int r = 0; r < 4; r++) {
            float v = SCALE * acc[n][r];
            if (valid) out1[o1base + (size_t)r * N_ + s] = v;
            acc[n][r] = valid ? v : -3e38f;
        }
    }

    // ---- softmax over s: reduce across lane15 (16-lane groups) ----
    float m[4], inv[4];
#pragma unroll
    for (int r = 0; r < 4; r++) {
        float mm = acc[0][r];
#pragma unroll
        for (int n = 1; n < 13; n++) mm = fmaxf(mm, acc[n][r]);
        mm = fmaxf(mm, __shfl_xor(mm, 1));
        mm = fmaxf(mm, __shfl_xor(mm, 2));
        mm = fmaxf(mm, __shfl_xor(mm, 4));
        mm = fmaxf(mm, __shfl_xor(mm, 8));
        m[r] = mm;
    }
#pragma unroll
    for (int r = 0; r < 4; r++) {
        float ss = 0.f;
#pragma unroll
        for (int n = 0; n < 13; n++) {
            float e = __expf(acc[n][r] - m[r]);   // masked -> exp(-huge) = 0
            acc[n][r] = e;
            ss += e;
        }
        ss += __shfl_xor(ss, 1);
        ss += __shfl_xor(ss, 2);
        ss += __shfl_xor(ss, 4);
        ss += __shfl_xor(ss, 8);
        inv[r] = 1.f / ss;
    }

    // ---- write normalized P (bf16) to own-wave LDS tile ----
#pragma unroll
    for (int n = 0; n < 13; n++)
#pragma unroll
        for (int r = 0; r < 4; r++)
            Pw[(quad * 4 + r) * 232 + n * 16 + lane15] = (bf16_t)(acc[n][r] * inv[r]);

    // ---- PV: x[16 q][64 d] = P[16][224] @ V[224][64], 7 k-chunks ----
    bf16x8 pa[7];
#pragma unroll
    for (int ks = 0; ks < 7; ks++)
        pa[ks] = *(const bf16x8*)(Pw + lane15 * 232 + ks * 32 + quad * 8);

    f32x4 o[4];
#pragma unroll
    for (int nt = 0; nt < 4; nt++) o[nt] = (f32x4){0.f, 0.f, 0.f, 0.f};
#pragma unroll
    for (int nt = 0; nt < 4; nt++)
#pragma unroll
        for (int ks = 0; ks < 7; ks++) {
            bf16x8 vb = *(const bf16x8*)(Vt + (nt * 16 + lane15) * 232 + ks * 32 + quad * 8);
            o[nt] = __builtin_amdgcn_mfma_f32_16x16x32_bf16(pa[ks], vb, o[nt], 0, 0, 0);
        }

    // o[nt][r]: row q = w*16 + quad*4 + r, col d = nt*16 + lane15
    const int qb2 = qt * 112 + w * 16 + quad * 4;
#pragma unroll
    for (int nt = 0; nt < 4; nt++)
#pragma unroll
        for (int r = 0; r < 4; r++)
            x[(((size_t)(b * Q_ + qb2 + r)) * F_ + f) * C_ + h * D_ + nt * 16 + lane15] =
                (bf16_t)o[nt][r];
}

// ---------------------------------------------------------------------------
// xsum[b,f,c] = sum_q x[b,q,f,c] (x in bf16). Grid (3, 8, 16). atomicAdd.
// ---------------------------------------------------------------------------
__global__ __launch_bounds__(256) void xsum_kernel(
    const bf16_t* __restrict__ x, float* __restrict__ xsum)
{
    const int c = blockIdx.x * 256 + threadIdx.x;
    const int qp = blockIdx.y, bf = blockIdx.z;
    const int b = bf >> 3, f = bf & 7;
    float s = 0.f;
    for (int j = 0; j < S_; j++) {
        int q = qp * S_ + j;
        s += (float)x[((size_t)(b * Q_ + q) * F_ + f) * C_ + c];
    }
    atomicAdd(&xsum[(size_t)bf * C_ + c], s);
}

// ---------------------------------------------------------------------------
// vsum[b,f,c2] = sum_c xsum[b,f,c] * Wpkv[c, 768+c2]. Grid 16 blocks.
// ---------------------------------------------------------------------------
__global__ __launch_bounds__(256) void vsum_kernel(
    const float* __restrict__ xsum, const float* __restrict__ Wpkv,
    float* __restrict__ vsum)
{
    __shared__ float xs[C_];
    const int bf = blockIdx.x;
    const int t = threadIdx.x;
    for (int i = 0; i < 3; i++) xs[t + 256 * i] = xsum[(size_t)bf * C_ + t + 256 * i];
    __syncthreads();
    for (int i = 0; i < 3; i++) {
        int c2 = t + 256 * i;
        float acc = 0.f;
        for (int c = 0; c < C_; c++) acc += xs[c] * Wpkv[(size_t)c * C2_ + C_ + c2];
        vsum[(size_t)bf * C_ + c2] = acc;
    }
}

// ---------------------------------------------------------------------------
// Stage-2: softmax over f, then qout[b,q,c] = sum_f p2 * vsum. Out bf16.
// ---------------------------------------------------------------------------
__global__ __launch_bounds__(256) void attn2_qout(
    const float* __restrict__ q2, const float* __restrict__ k2,
    const float* __restrict__ vsum, bf16_t* __restrict__ qout)
{
    __shared__ float q2s[C_];
    __shared__ float l2s[96];
    __shared__ float p2s[96];
    const int bq = blockIdx.x;
    const int t = threadIdx.x;
    for (int i = 0; i < 3; i++)
        q2s[t + 256 * i] = SCALE * q2[(size_t)bq * C_ + t + 256 * i];
    __syncthreads();

    if (t < 96) {
        int h = t >> 3, fr = t & 7;
        const float4* kr4 = (const float4*)(k2 + ((size_t)bq * F_ + fr) * C_ + h * D_);
        const float4* q4  = (const float4*)&q2s[h * D_];
        float acc = 0.f;
#pragma unroll
        for (int i = 0; i < 16; i++) {
            float4 kk = kr4[i], qq = q4[i];
            acc += kk.x * qq.x + kk.y * qq.y + kk.z * qq.z + kk.w * qq.w;
        }
        l2s[t] = acc;
    }
    __syncthreads();

    if (t < H_) {
        float mm = -3e38f;
#pragma unroll
        for (int fr = 0; fr < F_; fr++) mm = fmaxf(mm, l2s[t * 8 + fr]);
        float e[F_]; float ss = 0.f;
#pragma unroll
        for (int fr = 0; fr < F_; fr++) { e[fr] = __expf(l2s[t * 8 + fr] - mm); ss += e[fr]; }
        float inv = 1.f / ss;
#pragma unroll
        for (int fr = 0; fr < F_; fr++) p2s[t * 8 + fr] = e[fr] * inv;
    }
    __syncthreads();

    const int b = bq / Q_;
    for (int i = 0; i < 3; i++) {
        int c = t + 256 * i;
        int h = c >> 6;
        float acc = 0.f;
#pragma unroll
        for (int fr = 0; fr < F_; fr++)
            acc += p2s[h * 8 + fr] * vsum[((size_t)(b * F_ + fr)) * C_ + c];
        qout[(size_t)bq * C_ + c] = (bf16_t)acc;
    }
}

// ---------------------------------------------------------------------------
extern "C" void kernel_launch(void* const* d_in, const int* in_sizes, int n_in,
                              void* d_out, int out_size, void* d_ws, size_t ws_size,
                              hipStream_t stream) {
    const float* query  = (const float*)d_in[0];
    const float* memory = (const float*)d_in[1];
    const float* Wq     = (const float*)d_in[2];
    const float* Wkv    = (const float*)d_in[3];
    const float* Wpq    = (const float*)d_in[4];
    const float* Wpkv   = (const float*)d_in[5];
    const float* Wproj  = (const float*)d_in[6];
    const float* bproj  = (const float*)d_in[7];

    float* out0 = (float*)d_out;                              // [B,Q,C]
    float* out1 = (float*)d_out + (size_t)B_ * Q_ * C_;       // [B*H,Q,F,S]

    char* w = (char*)d_ws;                                    // byte offsets, all 16B aligned
    bf16_t* kv_bf = (bf16_t*)(w + 0);            //  9,633,792 B  [B*N, 2C] bf16 (reuses old qf slot)
    // (w + 9633792: 19,267,584 B old kvf fp32 slot — now unused)
    float*  q2f   = (float*) (w + 28901376);     //  9,633,792 B  [B*Q, C]
    float*  k2f   = (float*) (w + 38535168);     // 77,070,336 B  [B*Q*F, C]
    bf16_t* x_bf  = (bf16_t*)(w + 115605504);    // 38,535,168 B  [B*Q*F, C]
    bf16_t* qry_b = (bf16_t*)(w + 154140672);    //  4,816,896 B
    bf16_t* mem_b = (bf16_t*)(w + 158957568);    //  4,816,896 B
    bf16_t* q_bf  = (bf16_t*)(w + 163774464);    //  4,816,896 B
    bf16_t* qo_bf = (bf16_t*)(w + 168591360);    //  4,816,896 B
    bf16_t* Wqt   = (bf16_t*)(w + 173408256);    //  1,179,648 B  [768,768]
    bf16_t* Wkvt  = (bf16_t*)(w + 174587904);    //  2,359,296 B  [1536,768]
    bf16_t* Wpqt  = (bf16_t*)(w + 176947200);    //  1,179,648 B
    bf16_t* Wpkvt = (bf16_t*)(w + 178126848);    //  2,359,296 B  [1536,768]
    bf16_t* Wprjt = (bf16_t*)(w + 180486144);    //  1,179,648 B
    float*  xsum  = (float*) (w + 181665792);    //     49,152 B
    float*  vsum  = (float*) (w + 181714944);    //     49,152 B

    const int MQ = B_ * Q_;        // 3136
    const int MN = B_ * N_;        // 3136
    const int MX = B_ * Q_ * F_;   // 25088

    // input conversions
    cvt_bf16<<<2352, 256, 0, stream>>>(query,  qry_b, MQ * C_ / 4);
    cvt_bf16<<<2352, 256, 0, stream>>>(memory, mem_b, MN * C_ / 4);
    transpose_cvt<<<dim3(24, 24), 256, 0, stream>>>(Wq,    Wqt,   C_, C_);
    transpose_cvt<<<dim3(48, 24), 256, 0, stream>>>(Wkv,   Wkvt,  C_, C2_);
    transpose_cvt<<<dim3(24, 24), 256, 0, stream>>>(Wpq,   Wpqt,  C_, C_);
    transpose_cvt<<<dim3(48, 24), 256, 0, stream>>>(Wpkv,  Wpkvt, C_, C2_);
    transpose_cvt<<<dim3(24, 24), 256, 0, stream>>>(Wproj, Wprjt, C_, C_);

    // q = query @ Wq   (bf16 only — fused attn computes logits via MFMA)
    gemm_mfma<<<dim3(6, 25), 256, 0, stream>>>(qry_b, Wqt, nullptr, q_bf, MQ, C_, C_, nullptr);
    // kv = memory @ Wkv (bf16 only)
    gemm_mfma<<<dim3(12, 25), 256, 0, stream>>>(mem_b, Wkvt, nullptr, kv_bf, MN, C2_, C_, nullptr);
    // q2 = q @ Wpq (fp32 for attn2)
    gemm_mfma<<<dim3(6, 25), 256, 0, stream>>>(q_bf, Wpqt, q2f, nullptr, MQ, C_, C_, nullptr);
    // fused stage-1: logits (output 1) + softmax + PV -> x (bf16)
    attn1_fused<<<dim3(F_, 14, B_ * H_), 448, 0, stream>>>(q_bf, kv_bf, out1, x_bf);
    // k2 = x @ Wpkv[:, :768]
    gemm_mfma<<<dim3(6, 196), 256, 0, stream>>>(x_bf, Wpkvt, k2f, nullptr, MX, C_, C_, nullptr);
    // xsum over q, vsum = xsum @ Wpkv[:, 768:]
    hipMemsetAsync(xsum, 0, (size_t)B_ * F_ * C_ * sizeof(float), stream);
    xsum_kernel<<<dim3(3, 8, 16), 256, 0, stream>>>(x_bf, xsum);
    vsum_kernel<<<16, 256, 0, stream>>>(xsum, Wpkv, vsum);
    // stage-2 attention -> qout (bf16, pre-projection)
    attn2_qout<<<3136, 256, 0, stream>>>(q2f, k2f, vsum, qo_bf);
    // out0 = qout @ Wproj + bproj
    gemm_mfma<<<dim3(6, 25), 256, 0, stream>>>(qo_bf, Wprjt, out0, nullptr, MQ, C_, C_, bproj);
}

// Round 2
// 692.221 us; speedup vs baseline: 1.7832x; 1.0577x over previous
//
#include <hip/hip_runtime.h>

#define B_   2
#define Q_   1568
#define C_   768
#define C2_  1536
#define H_   12
#define D_   64
#define F_   8
#define S_   196
#define N_   1568
constexpr float SCALE = 0.125f;   // d^-0.5 = 64^-0.5

typedef __bf16 bf16_t;
typedef __bf16 bf16x8 __attribute__((ext_vector_type(8)));
typedef __bf16 bf16x4 __attribute__((ext_vector_type(4)));
typedef float  f32x4  __attribute__((ext_vector_type(4)));

#define AS_G __attribute__((address_space(1)))
#define AS_L __attribute__((address_space(3)))

__device__ inline void load_lds16(const void* g, void* l) {
    __builtin_amdgcn_global_load_lds((const AS_G unsigned int*)g,
                                     (AS_L unsigned int*)l, 16, 0, 0);
}

// ---------------------------------------------------------------------------
// fp32 -> bf16 elementwise convert (n % 4 == 0)
// ---------------------------------------------------------------------------
__global__ __launch_bounds__(256) void cvt_bf16(
    const float* __restrict__ in, bf16_t* __restrict__ out, int n4)
{
    int i = blockIdx.x * 256 + threadIdx.x;
    if (i < n4) {
        float4 v = ((const float4*)in)[i];
        bf16x4 o = { (bf16_t)v.x, (bf16_t)v.y, (bf16_t)v.z, (bf16_t)v.w };
        ((bf16x4*)out)[i] = o;
    }
}

// ---------------------------------------------------------------------------
// W[K,N] fp32 -> Wt[N,K] bf16 (transpose+convert). K,N % 32 == 0.
// ---------------------------------------------------------------------------
__global__ __launch_bounds__(256) void transpose_cvt(
    const float* __restrict__ W, bf16_t* __restrict__ Wt, int K, int N)
{
    __shared__ float tile[32][33];
    const int k0 = blockIdx.y * 32, n0 = blockIdx.x * 32;
    const int t = threadIdx.x;
    const int tx = t & 31, ty = t >> 5;          // ty 0..7
#pragma unroll
    for (int i = 0; i < 4; i++)
        tile[ty + i * 8][tx] = W[(size_t)(k0 + ty + i * 8) * N + n0 + tx];
    __syncthreads();
#pragma unroll
    for (int i = 0; i < 4; i++)
        Wt[(size_t)(n0 + ty + i * 8) * K + k0 + tx] = (bf16_t)tile[tx][ty + i * 8];
}

// ---------------------------------------------------------------------------
// bf16 MFMA GEMM: C[M,N] = A[M,K] @ Bt[N,K]^T (+bias). C fp32 optional,
// Cbf bf16 optional. 128x128 tile, BK=32, 256 threads.
// Double-buffered LDS: next-tile global_load_lds issued BEFORE ds_read+MFMA
// of current tile; single barrier per K-step (minimum 2-phase overlap).
// ---------------------------------------------------------------------------
__global__ __launch_bounds__(256) void gemm_mfma(
    const bf16_t* __restrict__ A, const bf16_t* __restrict__ Bt,
    float* __restrict__ C, bf16_t* __restrict__ Cbf,
    int M, int N, int K, const float* __restrict__ bias)
{
    __shared__ bf16_t As[2][128 * 32];
    __shared__ bf16_t Bs[2][128 * 32];
    const int n0 = blockIdx.x * 128;
    const int m0 = blockIdx.y * 128;
    const int t = threadIdx.x;
    const int lane = t & 63;
    const int wv = t >> 6;                 // wave 0..3
    const int wm = wv >> 1, wn = wv & 1;   // 2x2 wave grid, 64x64 each
    const int lane15 = lane & 15, quad = lane >> 4;

    f32x4 acc[4][4];
#pragma unroll
    for (int i = 0; i < 4; i++)
#pragma unroll
        for (int j = 0; j < 4; j++) acc[i][j] = (f32x4){0.f, 0.f, 0.f, 0.f};

    // per-thread staging sources (chunk c = half*256 + t; row=c>>2, kc=c&3)
    const int row0 = t >> 2,          kc0 = t & 3;
    const int row1 = (256 + t) >> 2,  kc1 = t & 3;
    int rg0 = m0 + row0; if (rg0 >= M) rg0 = M - 1;
    int rg1 = m0 + row1; if (rg1 >= M) rg1 = M - 1;
    const bf16_t* a0 = A  + (size_t)rg0 * K + kc0 * 8;
    const bf16_t* a1 = A  + (size_t)rg1 * K + kc1 * 8;
    const bf16_t* b0 = Bt + (size_t)(n0 + row0) * K + kc0 * 8;
    const bf16_t* b1 = Bt + (size_t)(n0 + row1) * K + kc1 * 8;
    const int dst0 = (0 * 256 + wv * 64) * 16;   // + lane*16 added by HW
    const int dst1 = (1 * 256 + wv * 64) * 16;

    auto stage = [&](int buf, int k0) {
        load_lds16(a0 + k0, (char*)As[buf] + dst0);
        load_lds16(b0 + k0, (char*)Bs[buf] + dst0);
        load_lds16(a1 + k0, (char*)As[buf] + dst1);
        load_lds16(b1 + k0, (char*)Bs[buf] + dst1);
    };

    stage(0, 0);
    __syncthreads();                       // buf0 resident
    int cur = 0;
    for (int k0 = 0; k0 < K; k0 += 32) {
        if (k0 + 32 < K) stage(cur ^ 1, k0 + 32);   // in flight during compute

        const bf16_t* Ab = As[cur];
        const bf16_t* Bb = Bs[cur];
        bf16x8 af[4], bfr[4];
#pragma unroll
        for (int i = 0; i < 4; i++) {
            af[i]  = *(const bf16x8*)(Ab + (wm * 64 + i * 16 + lane15) * 32 + quad * 8);
            bfr[i] = *(const bf16x8*)(Bb + (wn * 64 + i * 16 + lane15) * 32 + quad * 8);
        }
#pragma unroll
        for (int i = 0; i < 4; i++)
#pragma unroll
            for (int j = 0; j < 4; j++)
                acc[i][j] = __builtin_amdgcn_mfma_f32_16x16x32_bf16(af[i], bfr[j], acc[i][j], 0, 0, 0);

        __syncthreads();                   // drains next-tile stage; cur readable done
        cur ^= 1;
    }

#pragma unroll
    for (int i = 0; i < 4; i++) {
#pragma unroll
        for (int j = 0; j < 4; j++) {
            int col = n0 + wn * 64 + j * 16 + lane15;
            float bb = bias ? bias[col] : 0.f;
#pragma unroll
            for (int r = 0; r < 4; r++) {
                int row = m0 + wm * 64 + i * 16 + quad * 4 + r;
                if (row < M) {
                    float v = acc[i][j][r] + bb;
                    if (C)   C[(size_t)row * N + col] = v;
                    if (Cbf) Cbf[(size_t)row * N + col] = (bf16_t)v;
                }
            }
        }
    }
}

// ---------------------------------------------------------------------------
// Fused stage-1 attention: per (z=b*H+h, q-tile of 112, frame f):
//   S = scale * Q @ K^T  (MFMA)  -> write out1 (fp32)
//   P = softmax_s(S)     (wave-parallel shfl reduce)
//   x = P @ V            (MFMA, P via LDS bf16, V^T in LDS)
//   xsum += sum_q x      (LDS reduce + 64 global atomics per block)
// Grid (F=8, 14, 24), 448 threads (7 waves). LDS 81,664 B -> 2 blocks/CU.
// ---------------------------------------------------------------------------
__global__ __launch_bounds__(448, 4) void attn1_fused(
    const bf16_t* __restrict__ qb, const bf16_t* __restrict__ kvb,
    float* __restrict__ out1, bf16_t* __restrict__ x, float* __restrict__ xsum)
{
    __shared__ bf16_t Vt[64 * 232];          // V transposed: [d][s], s padded to 224
    __shared__ bf16_t Ps[7 * 16 * 232];      // per-wave P tile [16 q][s padded]
    const int f = blockIdx.x, qt = blockIdx.y, z = blockIdx.z;
    const int b = z / H_, h = z - b * H_;
    const int t = threadIdx.x;
    const int lane = t & 63, w = t >> 6;     // wave 0..6
    const int lane15 = lane & 15, quad = lane >> 4;

    const size_t kvBase = ((size_t)b * N_ + (size_t)f * S_) * C2_;

    // ---- Q A-frags hoisted: issue before staging so they fly under it ----
    const int qrow = qt * 112 + w * 16 + lane15;
    const bf16_t* qp = qb + ((size_t)b * Q_ + qrow) * C_ + h * D_ + quad * 8;
    bf16x8 qa0 = *(const bf16x8*)(qp);
    bf16x8 qa1 = *(const bf16x8*)(qp + 32);

    // ---- zero V pad cols s in [196,224) ----
#pragma unroll
    for (int i = 0; i < 4; i++) {
        int e = t + 448 * i;                 // 0..1791 = 64*28
        if (e < 64 * 28) {
            int dd = e / 28;
            int s  = S_ + (e - dd * 28);
            Vt[dd * 232 + s] = (bf16_t)0.f;
        }
    }
    // ---- stage V transposed: Vt[d][s] = V[s][d] ----
#pragma unroll
    for (int i = 0; i < 4; i++) {
        int e = t + 448 * i;                 // 0..1567 = 8*196
        if (e < 8 * S_) {
            int dg = e / S_, s = e - dg * S_;
            bf16x8 v = *(const bf16x8*)(kvb + kvBase + (size_t)s * C2_ + C_ + h * D_ + dg * 8);
#pragma unroll
            for (int j = 0; j < 8; j++)
                Vt[(dg * 8 + j) * 232 + s] = v[j];
        }
    }
    // ---- zero own-wave P pad cols [208,224) ----
    bf16_t* Pw = Ps + w * (16 * 232);
    {
        int prow = lane >> 2, c0 = 208 + (lane & 3) * 4;
        *(bf16x4*)(Pw + prow * 232 + c0) =
            (bf16x4){(bf16_t)0.f, (bf16_t)0.f, (bf16_t)0.f, (bf16_t)0.f};
    }
    __syncthreads();

    // ---- QK^T: 13 n-tiles of 16 keys, K frags loaded from global ----
    f32x4 acc[13];
#pragma unroll
    for (int n = 0; n < 13; n++) acc[n] = (f32x4){0.f, 0.f, 0.f, 0.f};
#pragma unroll
    for (int n = 0; n < 13; n++) {
        int srow = n * 16 + lane15; if (srow > S_ - 1) srow = S_ - 1;  // clamp pad rows
        const bf16_t* kp = kvb + kvBase + (size_t)srow * C2_ + h * D_ + quad * 8;
        bf16x8 kb0 = *(const bf16x8*)(kp);
        bf16x8 kb1 = *(const bf16x8*)(kp + 32);
        acc[n] = __builtin_amdgcn_mfma_f32_16x16x32_bf16(qa0, kb0, acc[n], 0, 0, 0);
        acc[n] = __builtin_amdgcn_mfma_f32_16x16x32_bf16(qa1, kb1, acc[n], 0, 0, 0);
    }

    // acc[n][r] = S[q = w*16 + quad*4 + r][s = n*16 + lane15]
    // ---- scale, write logits (output 1), mask pad ----
    const size_t o1base = ((size_t)z * Q_ + qt * 112 + w * 16 + quad * 4) * N_ + (size_t)f * S_;
#pragma unroll
    for (int n = 0; n < 13; n++) {
        int s = n * 16 + lane15;
        bool valid = s < S_;
#pragma unroll
        for (int r = 0; r < 4; r++) {
            float v = SCALE * acc[n][r];
            if (valid) out1[o1base + (size_t)r * N_ + s] = v;
            acc[n][r] = valid ? v : -3e38f;
        }
    }

    // ---- softmax over s: reduce across lane15 (16-lane groups) ----
    float m[4], inv[4];
#pragma unroll
    for (int r = 0; r < 4; r++) {
        float mm = acc[0][r];
#pragma unroll
        for (int n = 1; n < 13; n++) mm = fmaxf(mm, acc[n][r]);
        mm = fmaxf(mm, __shfl_xor(mm, 1));
        mm = fmaxf(mm, __shfl_xor(mm, 2));
        mm = fmaxf(mm, __shfl_xor(mm, 4));
        mm = fmaxf(mm, __shfl_xor(mm, 8));
        m[r] = mm;
    }
#pragma unroll
    for (int r = 0; r < 4; r++) {
        float ss = 0.f;
#pragma unroll
        for (int n = 0; n < 13; n++) {
            float e = __expf(acc[n][r] - m[r]);   // masked -> exp(-huge) = 0
            acc[n][r] = e;
            ss += e;
        }
        ss += __shfl_xor(ss, 1);
        ss += __shfl_xor(ss, 2);
        ss += __shfl_xor(ss, 4);
        ss += __shfl_xor(ss, 8);
        inv[r] = 1.f / ss;
    }

    // ---- write normalized P (bf16) to own-wave LDS tile ----
#pragma unroll
    for (int n = 0; n < 13; n++)
#pragma unroll
        for (int r = 0; r < 4; r++)
            Pw[(quad * 4 + r) * 232 + n * 16 + lane15] = (bf16_t)(acc[n][r] * inv[r]);

    // ---- PV: x[16 q][64 d] = P[16][224] @ V[224][64], 7 k-chunks ----
    bf16x8 pa[7];
#pragma unroll
    for (int ks = 0; ks < 7; ks++)
        pa[ks] = *(const bf16x8*)(Pw + lane15 * 232 + ks * 32 + quad * 8);

    f32x4 o[4];
#pragma unroll
    for (int nt = 0; nt < 4; nt++) o[nt] = (f32x4){0.f, 0.f, 0.f, 0.f};
#pragma unroll
    for (int nt = 0; nt < 4; nt++)
#pragma unroll
        for (int ks = 0; ks < 7; ks++) {
            bf16x8 vb = *(const bf16x8*)(Vt + (nt * 16 + lane15) * 232 + ks * 32 + quad * 8);
            o[nt] = __builtin_amdgcn_mfma_f32_16x16x32_bf16(pa[ks], vb, o[nt], 0, 0, 0);
        }

    // o[nt][r]: row q = w*16 + quad*4 + r, col d = nt*16 + lane15
    const int qb2 = qt * 112 + w * 16 + quad * 4;
#pragma unroll
    for (int nt = 0; nt < 4; nt++)
#pragma unroll
        for (int r = 0; r < 4; r++)
            x[(((size_t)(b * Q_ + qb2 + r)) * F_ + f) * C_ + h * D_ + nt * 16 + lane15] =
                (bf16_t)o[nt][r];

    // ---- fused xsum: block-level sum over its 112 q rows, then 64 atomics ----
    float part[4];
#pragma unroll
    for (int nt = 0; nt < 4; nt++)
        part[nt] = o[nt][0] + o[nt][1] + o[nt][2] + o[nt][3];
    __syncthreads();                       // Vt/Ps dead in all waves
    float* red = (float*)Vt;               // reuse LDS
    if (t < 64) red[t] = 0.f;
    __syncthreads();
#pragma unroll
    for (int nt = 0; nt < 4; nt++)
        atomicAdd(&red[nt * 16 + lane15], part[nt]);
    __syncthreads();
    if (t < 64)
        atomicAdd(&xsum[((size_t)(b * F_ + f)) * C_ + h * D_ + t], red[t]);
}

// ---------------------------------------------------------------------------
// vsum[b,f,c2] = sum_c xsum[b,f,c] * Wpkv[c, 768+c2]. Grid 16 blocks.
// ---------------------------------------------------------------------------
__global__ __launch_bounds__(256) void vsum_kernel(
    const float* __restrict__ xsum, const float* __restrict__ Wpkv,
    float* __restrict__ vsum)
{
    __shared__ float xs[C_];
    const int bf = blockIdx.x;
    const int t = threadIdx.x;
    for (int i = 0; i < 3; i++) xs[t + 256 * i] = xsum[(size_t)bf * C_ + t + 256 * i];
    __syncthreads();
    for (int i = 0; i < 3; i++) {
        int c2 = t + 256 * i;
        float acc = 0.f;
        for (int c = 0; c < C_; c++) acc += xs[c] * Wpkv[(size_t)c * C2_ + C_ + c2];
        vsum[(size_t)bf * C_ + c2] = acc;
    }
}

// ---------------------------------------------------------------------------
// Stage-2: softmax over f, then qout[b,q,c] = sum_f p2 * vsum. Out bf16.
// q2, k2 now bf16.
// ---------------------------------------------------------------------------
__global__ __launch_bounds__(256) void attn2_qout(
    const bf16_t* __restrict__ q2, const bf16_t* __restrict__ k2,
    const float* __restrict__ vsum, bf16_t* __restrict__ qout)
{
    __shared__ float q2s[C_];
    __shared__ float l2s[96];
    __shared__ float p2s[96];
    const int bq = blockIdx.x;
    const int t = threadIdx.x;
    for (int i = 0; i < 3; i++)
        q2s[t + 256 * i] = SCALE * (float)q2[(size_t)bq * C_ + t + 256 * i];
    __syncthreads();

    if (t < 96) {
        int h = t >> 3, fr = t & 7;
        const bf16x8* kr8 = (const bf16x8*)(k2 + ((size_t)bq * F_ + fr) * C_ + h * D_);
        float acc = 0.f;
#pragma unroll
        for (int i = 0; i < 8; i++) {
            bf16x8 kk = kr8[i];
#pragma unroll
            for (int j = 0; j < 8; j++) acc += (float)kk[j] * q2s[h * D_ + i * 8 + j];
        }
        l2s[t] = acc;
    }
    __syncthreads();

    if (t < H_) {
        float mm = -3e38f;
#pragma unroll
        for (int fr = 0; fr < F_; fr++) mm = fmaxf(mm, l2s[t * 8 + fr]);
        float e[F_]; float ss = 0.f;
#pragma unroll
        for (int fr = 0; fr < F_; fr++) { e[fr] = __expf(l2s[t * 8 + fr] - mm); ss += e[fr]; }
        float inv = 1.f / ss;
#pragma unroll
        for (int fr = 0; fr < F_; fr++) p2s[t * 8 + fr] = e[fr] * inv;
    }
    __syncthreads();

    const int b = bq / Q_;
    for (int i = 0; i < 3; i++) {
        int c = t + 256 * i;
        int h = c >> 6;
        float acc = 0.f;
#pragma unroll
        for (int fr = 0; fr < F_; fr++)
            acc += p2s[h * 8 + fr] * vsum[((size_t)(b * F_ + fr)) * C_ + c];
        qout[(size_t)bq * C_ + c] = (bf16_t)acc;
    }
}

// ---------------------------------------------------------------------------
extern "C" void kernel_launch(void* const* d_in, const int* in_sizes, int n_in,
                              void* d_out, int out_size, void* d_ws, size_t ws_size,
                              hipStream_t stream) {
    const float* query  = (const float*)d_in[0];
    const float* memory = (const float*)d_in[1];
    const float* Wq     = (const float*)d_in[2];
    const float* Wkv    = (const float*)d_in[3];
    const float* Wpq    = (const float*)d_in[4];
    const float* Wpkv   = (const float*)d_in[5];
    const float* Wproj  = (const float*)d_in[6];
    const float* bproj  = (const float*)d_in[7];

    float* out0 = (float*)d_out;                              // [B,Q,C]
    float* out1 = (float*)d_out + (size_t)B_ * Q_ * C_;       // [B*H,Q,F,S]

    char* w = (char*)d_ws;                                    // byte offsets, all 16B aligned
    bf16_t* kv_bf = (bf16_t*)(w + 0);            //  9,633,792 B  [B*N, 2C] bf16
    bf16_t* q2b   = (bf16_t*)(w + 28901376);     //  4,816,896 B  [B*Q, C] bf16
    bf16_t* k2b   = (bf16_t*)(w + 38535168);     // 38,535,168 B  [B*Q*F, C] bf16
    bf16_t* x_bf  = (bf16_t*)(w + 115605504);    // 38,535,168 B  [B*Q*F, C]
    bf16_t* qry_b = (bf16_t*)(w + 154140672);    //  4,816,896 B
    bf16_t* mem_b = (bf16_t*)(w + 158957568);    //  4,816,896 B
    bf16_t* q_bf  = (bf16_t*)(w + 163774464);    //  4,816,896 B
    bf16_t* qo_bf = (bf16_t*)(w + 168591360);    //  4,816,896 B
    bf16_t* Wqt   = (bf16_t*)(w + 173408256);    //  1,179,648 B  [768,768]
    bf16_t* Wkvt  = (bf16_t*)(w + 174587904);    //  2,359,296 B  [1536,768]
    bf16_t* Wpqt  = (bf16_t*)(w + 176947200);    //  1,179,648 B
    bf16_t* Wpkvt = (bf16_t*)(w + 178126848);    //  2,359,296 B  [1536,768]
    bf16_t* Wprjt = (bf16_t*)(w + 180486144);    //  1,179,648 B
    float*  xsum  = (float*) (w + 181665792);    //     49,152 B
    float*  vsum  = (float*) (w + 181714944);    //     49,152 B

    const int MQ = B_ * Q_;        // 3136
    const int MN = B_ * N_;        // 3136
    const int MX = B_ * Q_ * F_;   // 25088

    // input conversions
    cvt_bf16<<<2352, 256, 0, stream>>>(query,  qry_b, MQ * C_ / 4);
    cvt_bf16<<<2352, 256, 0, stream>>>(memory, mem_b, MN * C_ / 4);
    transpose_cvt<<<dim3(24, 24), 256, 0, stream>>>(Wq,    Wqt,   C_, C_);
    transpose_cvt<<<dim3(48, 24), 256, 0, stream>>>(Wkv,   Wkvt,  C_, C2_);
    transpose_cvt<<<dim3(24, 24), 256, 0, stream>>>(Wpq,   Wpqt,  C_, C_);
    transpose_cvt<<<dim3(48, 24), 256, 0, stream>>>(Wpkv,  Wpkvt, C_, C2_);
    transpose_cvt<<<dim3(24, 24), 256, 0, stream>>>(Wproj, Wprjt, C_, C_);

    // q = query @ Wq (bf16)
    gemm_mfma<<<dim3(6, 25), 256, 0, stream>>>(qry_b, Wqt, nullptr, q_bf, MQ, C_, C_, nullptr);
    // kv = memory @ Wkv (bf16)
    gemm_mfma<<<dim3(12, 25), 256, 0, stream>>>(mem_b, Wkvt, nullptr, kv_bf, MN, C2_, C_, nullptr);
    // q2 = q @ Wpq (bf16)
    gemm_mfma<<<dim3(6, 25), 256, 0, stream>>>(q_bf, Wpqt, nullptr, q2b, MQ, C_, C_, nullptr);
    // fused stage-1: logits (output 1) + softmax + PV -> x (bf16) + xsum
    hipMemsetAsync(xsum, 0, (size_t)B_ * F_ * C_ * sizeof(float), stream);
    attn1_fused<<<dim3(F_, 14, B_ * H_), 448, 0, stream>>>(q_bf, kv_bf, out1, x_bf, xsum);
    // k2 = x @ Wpkv[:, :768]  (bf16)
    gemm_mfma<<<dim3(6, 196), 256, 0, stream>>>(x_bf, Wpkvt, nullptr, k2b, MX, C_, C_, nullptr);
    // vsum = xsum @ Wpkv[:, 768:]
    vsum_kernel<<<16, 256, 0, stream>>>(xsum, Wpkv, vsum);
    // stage-2 attention -> qout (bf16, pre-projection)
    attn2_qout<<<3136, 256, 0, stream>>>(q2b, k2b, vsum, qo_bf);
    // out0 = qout @ Wproj + bproj
    gemm_mfma<<<dim3(6, 25), 256, 0, stream>>>(qo_bf, Wprjt, out0, nullptr, MQ, C_, C_, bproj);
}

// Round 3
// 620.163 us; speedup vs baseline: 1.9904x; 1.1162x over previous
//
#include <hip/hip_runtime.h>

#define B_   2
#define Q_   1568
#define C_   768
#define C2_  1536
#define H_   12
#define D_   64
#define F_   8
#define S_   196
#define N_   1568
constexpr float SCALE = 0.125f;   // d^-0.5 = 64^-0.5

typedef __bf16 bf16_t;
typedef __bf16 bf16x8 __attribute__((ext_vector_type(8)));
typedef __bf16 bf16x4 __attribute__((ext_vector_type(4)));
typedef float  f32x4  __attribute__((ext_vector_type(4)));

#define AS_G __attribute__((address_space(1)))
#define AS_L __attribute__((address_space(3)))

__device__ inline void load_lds16(const void* g, void* l) {
    __builtin_amdgcn_global_load_lds((const AS_G unsigned int*)g,
                                     (AS_L unsigned int*)l, 16, 0, 0);
}

// ---------------------------------------------------------------------------
// fp32 -> bf16 elementwise convert (n % 4 == 0)
// ---------------------------------------------------------------------------
__global__ __launch_bounds__(256) void cvt_bf16(
    const float* __restrict__ in, bf16_t* __restrict__ out, int n4)
{
    int i = blockIdx.x * 256 + threadIdx.x;
    if (i < n4) {
        float4 v = ((const float4*)in)[i];
        bf16x4 o = { (bf16_t)v.x, (bf16_t)v.y, (bf16_t)v.z, (bf16_t)v.w };
        ((bf16x4*)out)[i] = o;
    }
}

// ---------------------------------------------------------------------------
// W[K,N] fp32 -> Wt[N,K] bf16 (transpose+convert). K,N % 32 == 0.
// ---------------------------------------------------------------------------
__global__ __launch_bounds__(256) void transpose_cvt(
    const float* __restrict__ W, bf16_t* __restrict__ Wt, int K, int N)
{
    __shared__ float tile[32][33];
    const int k0 = blockIdx.y * 32, n0 = blockIdx.x * 32;
    const int t = threadIdx.x;
    const int tx = t & 31, ty = t >> 5;          // ty 0..7
#pragma unroll
    for (int i = 0; i < 4; i++)
        tile[ty + i * 8][tx] = W[(size_t)(k0 + ty + i * 8) * N + n0 + tx];
    __syncthreads();
#pragma unroll
    for (int i = 0; i < 4; i++)
        Wt[(size_t)(n0 + ty + i * 8) * K + k0 + tx] = (bf16_t)tile[tx][ty + i * 8];
}

// ---------------------------------------------------------------------------
// bf16 MFMA GEMM: C[M,N] = A[M,K] @ Bt[N,K]^T (+bias). C fp32 optional,
// Cbf bf16 optional. 128x128 tile, BK=32, 256 threads, double-buffered.
// Optional fused logits2 epilogue (for the k2 GEMM): when l2out != nullptr,
// rows are (bq, f) pairs (row = bq*8+f), cols are head-dims, and the kernel
// emits l2out[bq*H*F + h*F + f] = SCALE * sum_c q2e[bq,c]*acc[row,c]
// instead of storing C. Each (row, head) is fully contained in one wave
// (64 cols = j*16+lane15), so stores are exact-once, no atomics.
// ---------------------------------------------------------------------------
__global__ __launch_bounds__(256) void gemm_mfma(
    const bf16_t* __restrict__ A, const bf16_t* __restrict__ Bt,
    float* __restrict__ C, bf16_t* __restrict__ Cbf,
    int M, int N, int K, const float* __restrict__ bias,
    const bf16_t* __restrict__ q2e, float* __restrict__ l2out)
{
    __shared__ bf16_t As[2][128 * 32];
    __shared__ bf16_t Bs[2][128 * 32];
    const int n0 = blockIdx.x * 128;
    const int m0 = blockIdx.y * 128;
    const int t = threadIdx.x;
    const int lane = t & 63;
    const int wv = t >> 6;                 // wave 0..3
    const int wm = wv >> 1, wn = wv & 1;   // 2x2 wave grid, 64x64 each
    const int lane15 = lane & 15, quad = lane >> 4;

    f32x4 acc[4][4];
#pragma unroll
    for (int i = 0; i < 4; i++)
#pragma unroll
        for (int j = 0; j < 4; j++) acc[i][j] = (f32x4){0.f, 0.f, 0.f, 0.f};

    // per-thread staging sources (chunk c = half*256 + t; row=c>>2, kc=c&3)
    const int row0 = t >> 2,          kc0 = t & 3;
    const int row1 = (256 + t) >> 2,  kc1 = t & 3;
    int rg0 = m0 + row0; if (rg0 >= M) rg0 = M - 1;
    int rg1 = m0 + row1; if (rg1 >= M) rg1 = M - 1;
    const bf16_t* a0 = A  + (size_t)rg0 * K + kc0 * 8;
    const bf16_t* a1 = A  + (size_t)rg1 * K + kc1 * 8;
    const bf16_t* b0 = Bt + (size_t)(n0 + row0) * K + kc0 * 8;
    const bf16_t* b1 = Bt + (size_t)(n0 + row1) * K + kc1 * 8;
    const int dst0 = (0 * 256 + wv * 64) * 16;   // + lane*16 added by HW
    const int dst1 = (1 * 256 + wv * 64) * 16;

    auto stage = [&](int buf, int k0) {
        load_lds16(a0 + k0, (char*)As[buf] + dst0);
        load_lds16(b0 + k0, (char*)Bs[buf] + dst0);
        load_lds16(a1 + k0, (char*)As[buf] + dst1);
        load_lds16(b1 + k0, (char*)Bs[buf] + dst1);
    };

    stage(0, 0);
    __syncthreads();                       // buf0 resident
    int cur = 0;
    for (int k0 = 0; k0 < K; k0 += 32) {
        if (k0 + 32 < K) stage(cur ^ 1, k0 + 32);   // in flight during compute

        const bf16_t* Ab = As[cur];
        const bf16_t* Bb = Bs[cur];
        bf16x8 af[4], bfr[4];
#pragma unroll
        for (int i = 0; i < 4; i++) {
            af[i]  = *(const bf16x8*)(Ab + (wm * 64 + i * 16 + lane15) * 32 + quad * 8);
            bfr[i] = *(const bf16x8*)(Bb + (wn * 64 + i * 16 + lane15) * 32 + quad * 8);
        }
#pragma unroll
        for (int i = 0; i < 4; i++)
#pragma unroll
            for (int j = 0; j < 4; j++)
                acc[i][j] = __builtin_amdgcn_mfma_f32_16x16x32_bf16(af[i], bfr[j], acc[i][j], 0, 0, 0);

        __syncthreads();                   // drains next-tile stage; cur readable done
        cur ^= 1;
    }

    if (C || Cbf) {
#pragma unroll
        for (int i = 0; i < 4; i++) {
#pragma unroll
            for (int j = 0; j < 4; j++) {
                int col = n0 + wn * 64 + j * 16 + lane15;
                float bb = bias ? bias[col] : 0.f;
#pragma unroll
                for (int r = 0; r < 4; r++) {
                    int row = m0 + wm * 64 + i * 16 + quad * 4 + r;
                    if (row < M) {
                        float v = acc[i][j][r] + bb;
                        if (C)   C[(size_t)row * N + col] = v;
                        if (Cbf) Cbf[(size_t)row * N + col] = (bf16_t)v;
                    }
                }
            }
        }
    }

    if (l2out) {
        // stage q2 tile [16 bq rows][128 cols] as fp32 into As LDS
        float* q2s = (float*)As;           // 16*128*4 = 8 KB
        {
            int qi = t >> 4, cg = t & 15;  // 16 x 16
            int bq = (m0 >> 3) + qi;       // m0 % 8 == 0 by construction
            bf16x8 v = *(const bf16x8*)(q2e + (size_t)bq * C_ + n0 + cg * 8);
#pragma unroll
            for (int j = 0; j < 8; j++) q2s[qi * 128 + cg * 8 + j] = (float)v[j];
        }
        __syncthreads();
        const int hh = (n0 >> 6) + wn;
#pragma unroll
        for (int i = 0; i < 4; i++) {
#pragma unroll
            for (int r = 0; r < 4; r++) {
                int row = wm * 64 + i * 16 + quad * 4 + r;   // local m-row
                int qi = row >> 3;
                float s = 0.f;
#pragma unroll
                for (int j = 0; j < 4; j++)
                    s += acc[i][j][r] * q2s[qi * 128 + wn * 64 + j * 16 + lane15];
                s += __shfl_xor(s, 1);
                s += __shfl_xor(s, 2);
                s += __shfl_xor(s, 4);
                s += __shfl_xor(s, 8);
                if (lane15 == 0) {
                    int grow = m0 + row;
                    l2out[((size_t)(grow >> 3) * H_ + hh) * F_ + (grow & 7)] = SCALE * s;
                }
            }
        }
    }
}

// ---------------------------------------------------------------------------
// Fused stage-1 attention (unchanged from round 2): QK^T -> out1, softmax,
// PV -> x, fused xsum. Grid (F=8, 14, 24), 448 threads.
// ---------------------------------------------------------------------------
__global__ __launch_bounds__(448, 4) void attn1_fused(
    const bf16_t* __restrict__ qb, const bf16_t* __restrict__ kvb,
    float* __restrict__ out1, bf16_t* __restrict__ x, float* __restrict__ xsum)
{
    __shared__ bf16_t Vt[64 * 232];          // V transposed: [d][s], s padded to 224
    __shared__ bf16_t Ps[7 * 16 * 232];      // per-wave P tile [16 q][s padded]
    const int f = blockIdx.x, qt = blockIdx.y, z = blockIdx.z;
    const int b = z / H_, h = z - b * H_;
    const int t = threadIdx.x;
    const int lane = t & 63, w = t >> 6;     // wave 0..6
    const int lane15 = lane & 15, quad = lane >> 4;

    const size_t kvBase = ((size_t)b * N_ + (size_t)f * S_) * C2_;

    // ---- Q A-frags hoisted: issue before staging so they fly under it ----
    const int qrow = qt * 112 + w * 16 + lane15;
    const bf16_t* qp = qb + ((size_t)b * Q_ + qrow) * C_ + h * D_ + quad * 8;
    bf16x8 qa0 = *(const bf16x8*)(qp);
    bf16x8 qa1 = *(const bf16x8*)(qp + 32);

    // ---- zero V pad cols s in [196,224) ----
#pragma unroll
    for (int i = 0; i < 4; i++) {
        int e = t + 448 * i;                 // 0..1791 = 64*28
        if (e < 64 * 28) {
            int dd = e / 28;
            int s  = S_ + (e - dd * 28);
            Vt[dd * 232 + s] = (bf16_t)0.f;
        }
    }
    // ---- stage V transposed: Vt[d][s] = V[s][d] ----
#pragma unroll
    for (int i = 0; i < 4; i++) {
        int e = t + 448 * i;                 // 0..1567 = 8*196
        if (e < 8 * S_) {
            int dg = e / S_, s = e - dg * S_;
            bf16x8 v = *(const bf16x8*)(kvb + kvBase + (size_t)s * C2_ + C_ + h * D_ + dg * 8);
#pragma unroll
            for (int j = 0; j < 8; j++)
                Vt[(dg * 8 + j) * 232 + s] = v[j];
        }
    }
    // ---- zero own-wave P pad cols [208,224) ----
    bf16_t* Pw = Ps + w * (16 * 232);
    {
        int prow = lane >> 2, c0 = 208 + (lane & 3) * 4;
        *(bf16x4*)(Pw + prow * 232 + c0) =
            (bf16x4){(bf16_t)0.f, (bf16_t)0.f, (bf16_t)0.f, (bf16_t)0.f};
    }
    __syncthreads();

    // ---- QK^T: 13 n-tiles of 16 keys, K frags loaded from global ----
    f32x4 acc[13];
#pragma unroll
    for (int n = 0; n < 13; n++) acc[n] = (f32x4){0.f, 0.f, 0.f, 0.f};
#pragma unroll
    for (int n = 0; n < 13; n++) {
        int srow = n * 16 + lane15; if (srow > S_ - 1) srow = S_ - 1;  // clamp pad rows
        const bf16_t* kp = kvb + kvBase + (size_t)srow * C2_ + h * D_ + quad * 8;
        bf16x8 kb0 = *(const bf16x8*)(kp);
        bf16x8 kb1 = *(const bf16x8*)(kp + 32);
        acc[n] = __builtin_amdgcn_mfma_f32_16x16x32_bf16(qa0, kb0, acc[n], 0, 0, 0);
        acc[n] = __builtin_amdgcn_mfma_f32_16x16x32_bf16(qa1, kb1, acc[n], 0, 0, 0);
    }

    // acc[n][r] = S[q = w*16 + quad*4 + r][s = n*16 + lane15]
    // ---- scale, write logits (output 1), mask pad ----
    const size_t o1base = ((size_t)z * Q_ + qt * 112 + w * 16 + quad * 4) * N_ + (size_t)f * S_;
#pragma unroll
    for (int n = 0; n < 13; n++) {
        int s = n * 16 + lane15;
        bool valid = s < S_;
#pragma unroll
        for (int r = 0; r < 4; r++) {
            float v = SCALE * acc[n][r];
            if (valid) out1[o1base + (size_t)r * N_ + s] = v;
            acc[n][r] = valid ? v : -3e38f;
        }
    }

    // ---- softmax over s: reduce across lane15 (16-lane groups) ----
    float m[4], inv[4];
#pragma unroll
    for (int r = 0; r < 4; r++) {
        float mm = acc[0][r];
#pragma unroll
        for (int n = 1; n < 13; n++) mm = fmaxf(mm, acc[n][r]);
        mm = fmaxf(mm, __shfl_xor(mm, 1));
        mm = fmaxf(mm, __shfl_xor(mm, 2));
        mm = fmaxf(mm, __shfl_xor(mm, 4));
        mm = fmaxf(mm, __shfl_xor(mm, 8));
        m[r] = mm;
    }
#pragma unroll
    for (int r = 0; r < 4; r++) {
        float ss = 0.f;
#pragma unroll
        for (int n = 0; n < 13; n++) {
            float e = __expf(acc[n][r] - m[r]);   // masked -> exp(-huge) = 0
            acc[n][r] = e;
            ss += e;
        }
        ss += __shfl_xor(ss, 1);
        ss += __shfl_xor(ss, 2);
        ss += __shfl_xor(ss, 4);
        ss += __shfl_xor(ss, 8);
        inv[r] = 1.f / ss;
    }

    // ---- write normalized P (bf16) to own-wave LDS tile ----
#pragma unroll
    for (int n = 0; n < 13; n++)
#pragma unroll
        for (int r = 0; r < 4; r++)
            Pw[(quad * 4 + r) * 232 + n * 16 + lane15] = (bf16_t)(acc[n][r] * inv[r]);

    // ---- PV: x[16 q][64 d] = P[16][224] @ V[224][64], 7 k-chunks ----
    bf16x8 pa[7];
#pragma unroll
    for (int ks = 0; ks < 7; ks++)
        pa[ks] = *(const bf16x8*)(Pw + lane15 * 232 + ks * 32 + quad * 8);

    f32x4 o[4];
#pragma unroll
    for (int nt = 0; nt < 4; nt++) o[nt] = (f32x4){0.f, 0.f, 0.f, 0.f};
#pragma unroll
    for (int nt = 0; nt < 4; nt++)
#pragma unroll
        for (int ks = 0; ks < 7; ks++) {
            bf16x8 vb = *(const bf16x8*)(Vt + (nt * 16 + lane15) * 232 + ks * 32 + quad * 8);
            o[nt] = __builtin_amdgcn_mfma_f32_16x16x32_bf16(pa[ks], vb, o[nt], 0, 0, 0);
        }

    // o[nt][r]: row q = w*16 + quad*4 + r, col d = nt*16 + lane15
    const int qb2 = qt * 112 + w * 16 + quad * 4;
#pragma unroll
    for (int nt = 0; nt < 4; nt++)
#pragma unroll
        for (int r = 0; r < 4; r++)
            x[(((size_t)(b * Q_ + qb2 + r)) * F_ + f) * C_ + h * D_ + nt * 16 + lane15] =
                (bf16_t)o[nt][r];

    // ---- fused xsum: block-level sum over its 112 q rows, then 64 atomics ----
    float part[4];
#pragma unroll
    for (int nt = 0; nt < 4; nt++)
        part[nt] = o[nt][0] + o[nt][1] + o[nt][2] + o[nt][3];
    __syncthreads();                       // Vt/Ps dead in all waves
    float* red = (float*)Vt;               // reuse LDS
    if (t < 64) red[t] = 0.f;
    __syncthreads();
#pragma unroll
    for (int nt = 0; nt < 4; nt++)
        atomicAdd(&red[nt * 16 + lane15], part[nt]);
    __syncthreads();
    if (t < 64)
        atomicAdd(&xsum[((size_t)(b * F_ + f)) * C_ + h * D_ + t], red[t]);
}

// ---------------------------------------------------------------------------
// vsum[b,f,c2] = sum_c xsum[b,f,c] * Wpkv[c, 768+c2]. Grid (16, 3).
// ---------------------------------------------------------------------------
__global__ __launch_bounds__(256) void vsum_kernel(
    const float* __restrict__ xsum, const float* __restrict__ Wpkv,
    float* __restrict__ vsum)
{
    __shared__ float xs[C_];
    const int bf = blockIdx.x;
    const int t = threadIdx.x;
    for (int i = 0; i < 3; i++) xs[t + 256 * i] = xsum[(size_t)bf * C_ + t + 256 * i];
    __syncthreads();
    const int c2 = blockIdx.y * 256 + t;
    float acc = 0.f;
#pragma unroll 8
    for (int c = 0; c < C_; c++) acc += xs[c] * Wpkv[(size_t)c * C2_ + C_ + c2];
    vsum[(size_t)bf * C_ + c2] = acc;
}

// ---------------------------------------------------------------------------
// Stage-2: softmax over f (logits precomputed by k2-GEMM epilogue), then
// qout[b,q,c] = sum_f p2 * vsum. Out bf16. Grid 3136 blocks.
// ---------------------------------------------------------------------------
__global__ __launch_bounds__(256) void attn2_qout(
    const float* __restrict__ logits2, const float* __restrict__ vsum,
    bf16_t* __restrict__ qout)
{
    __shared__ float p2s[96];
    const int bq = blockIdx.x;
    const int t = threadIdx.x;

    if (t < 96) {                           // t = h*8 + f
        float l = logits2[(size_t)bq * 96 + t];
        float mm = l;
        mm = fmaxf(mm, __shfl_xor(mm, 1));
        mm = fmaxf(mm, __shfl_xor(mm, 2));
        mm = fmaxf(mm, __shfl_xor(mm, 4));  // 8-lane group (same h) max
        float e = __expf(l - mm);
        float ss = e;
        ss += __shfl_xor(ss, 1);
        ss += __shfl_xor(ss, 2);
        ss += __shfl_xor(ss, 4);
        p2s[t] = e / ss;
    }
    __syncthreads();

    const int b = bq / Q_;
    for (int i = 0; i < 3; i++) {
        int c = t + 256 * i;
        int h = c >> 6;
        float acc = 0.f;
#pragma unroll
        for (int fr = 0; fr < F_; fr++)
            acc += p2s[h * 8 + fr] * vsum[((size_t)(b * F_ + fr)) * C_ + c];
        qout[(size_t)bq * C_ + c] = (bf16_t)acc;
    }
}

// ---------------------------------------------------------------------------
extern "C" void kernel_launch(void* const* d_in, const int* in_sizes, int n_in,
                              void* d_out, int out_size, void* d_ws, size_t ws_size,
                              hipStream_t stream) {
    const float* query  = (const float*)d_in[0];
    const float* memory = (const float*)d_in[1];
    const float* Wq     = (const float*)d_in[2];
    const float* Wkv    = (const float*)d_in[3];
    const float* Wpq    = (const float*)d_in[4];
    const float* Wpkv   = (const float*)d_in[5];
    const float* Wproj  = (const float*)d_in[6];
    const float* bproj  = (const float*)d_in[7];

    float* out0 = (float*)d_out;                              // [B,Q,C]
    float* out1 = (float*)d_out + (size_t)B_ * Q_ * C_;       // [B*H,Q,F,S]

    char* w = (char*)d_ws;                                    // byte offsets, all 16B aligned
    bf16_t* kv_bf = (bf16_t*)(w + 0);            //  9,633,792 B  [B*N, 2C] bf16
    bf16_t* q2b   = (bf16_t*)(w + 28901376);     //  4,816,896 B  [B*Q, C] bf16
    float*  lgt2  = (float*) (w + 38535168);     //  1,204,224 B  [B*Q, H, F] fp32
    bf16_t* x_bf  = (bf16_t*)(w + 115605504);    // 38,535,168 B  [B*Q*F, C]
    bf16_t* qry_b = (bf16_t*)(w + 154140672);    //  4,816,896 B
    bf16_t* mem_b = (bf16_t*)(w + 158957568);    //  4,816,896 B
    bf16_t* q_bf  = (bf16_t*)(w + 163774464);    //  4,816,896 B
    bf16_t* qo_bf = (bf16_t*)(w + 168591360);    //  4,816,896 B
    bf16_t* Wqt   = (bf16_t*)(w + 173408256);    //  1,179,648 B  [768,768]
    bf16_t* Wkvt  = (bf16_t*)(w + 174587904);    //  2,359,296 B  [1536,768]
    bf16_t* Wpqt  = (bf16_t*)(w + 176947200);    //  1,179,648 B
    bf16_t* Wpkvt = (bf16_t*)(w + 178126848);    //  2,359,296 B  [1536,768]
    bf16_t* Wprjt = (bf16_t*)(w + 180486144);    //  1,179,648 B
    float*  xsum  = (float*) (w + 181665792);    //     49,152 B
    float*  vsum  = (float*) (w + 181714944);    //     49,152 B

    const int MQ = B_ * Q_;        // 3136
    const int MN = B_ * N_;        // 3136
    const int MX = B_ * Q_ * F_;   // 25088

    // input conversions
    cvt_bf16<<<2352, 256, 0, stream>>>(query,  qry_b, MQ * C_ / 4);
    cvt_bf16<<<2352, 256, 0, stream>>>(memory, mem_b, MN * C_ / 4);
    transpose_cvt<<<dim3(24, 24), 256, 0, stream>>>(Wq,    Wqt,   C_, C_);
    transpose_cvt<<<dim3(48, 24), 256, 0, stream>>>(Wkv,   Wkvt,  C_, C2_);
    transpose_cvt<<<dim3(24, 24), 256, 0, stream>>>(Wpq,   Wpqt,  C_, C_);
    transpose_cvt<<<dim3(48, 24), 256, 0, stream>>>(Wpkv,  Wpkvt, C_, C2_);
    transpose_cvt<<<dim3(24, 24), 256, 0, stream>>>(Wproj, Wprjt, C_, C_);

    // q = query @ Wq (bf16)
    gemm_mfma<<<dim3(6, 25), 256, 0, stream>>>(qry_b, Wqt, nullptr, q_bf, MQ, C_, C_, nullptr, nullptr, nullptr);
    // kv = memory @ Wkv (bf16)
    gemm_mfma<<<dim3(12, 25), 256, 0, stream>>>(mem_b, Wkvt, nullptr, kv_bf, MN, C2_, C_, nullptr, nullptr, nullptr);
    // q2 = q @ Wpq (bf16)
    gemm_mfma<<<dim3(6, 25), 256, 0, stream>>>(q_bf, Wpqt, nullptr, q2b, MQ, C_, C_, nullptr, nullptr, nullptr);
    // fused stage-1: logits (output 1) + softmax + PV -> x (bf16) + xsum
    hipMemsetAsync(xsum, 0, (size_t)B_ * F_ * C_ * sizeof(float), stream);
    attn1_fused<<<dim3(F_, 14, B_ * H_), 448, 0, stream>>>(q_bf, kv_bf, out1, x_bf, xsum);
    // k2 GEMM with fused stage-2 logits epilogue (k2 never materialized)
    gemm_mfma<<<dim3(6, 196), 256, 0, stream>>>(x_bf, Wpkvt, nullptr, nullptr, MX, C_, C_, nullptr, q2b, lgt2);
    // vsum = xsum @ Wpkv[:, 768:]
    vsum_kernel<<<dim3(16, 3), 256, 0, stream>>>(xsum, Wpkv, vsum);
    // stage-2 attention -> qout (bf16, pre-projection)
    attn2_qout<<<3136, 256, 0, stream>>>(lgt2, vsum, qo_bf);
    // out0 = qout @ Wproj + bproj
    gemm_mfma<<<dim3(6, 25), 256, 0, stream>>>(qo_bf, Wprjt, out0, nullptr, MQ, C_, C_, bproj, nullptr, nullptr);
}